// Round 12
// baseline (1337.294 us; speedup 1.0000x reference)
//
#include <hip/hip_runtime.h>

#define NN 100000
#define CC 128
#define EE 1600000
#define GG 1024
#define LL 5

typedef __attribute__((ext_vector_type(8))) short bf16x8;
typedef __attribute__((ext_vector_type(16))) float f32x16;

__device__ __forceinline__ float sigmoidf_(float x) { return 1.0f / (1.0f + __expf(-x)); }
__device__ __forceinline__ float tanhf_(float x) {
  float xx = fminf(15.0f, fmaxf(-15.0f, x));
  float t = __expf(-2.0f * xx);
  return (1.0f - t) / (1.0f + t);
}
__device__ __forceinline__ unsigned short f2bf(float x) {
  unsigned int u = __float_as_uint(x);
  return (unsigned short)((u + 0x7fffu + ((u >> 16) & 1u)) >> 16);
}
__device__ __forceinline__ float bflo(unsigned int u) { return __uint_as_float(u << 16); }
__device__ __forceinline__ float bfhi(unsigned int u) { return __uint_as_float(u & 0xffff0000u); }
__device__ __forceinline__ float bf2f(unsigned short v) { return __uint_as_float((unsigned)v << 16); }

// ---------------- fused prepack + zero-init kernel (one launch) ----------------
// 32x32x16 packed B layout: element (k, o) at t = ((cb*8+ks)*64 + l)*8 + i
// with k = ks*16 + 8*(l>>5) + i, o = cb*32 + (l&31); cb in [0,12): r=0..3, z=4..7, n=8..11.
#define PK_WHH 192
#define PK_FUSE (192 * LL)
#define PK_DEG ((NN + 256 + 255) / 256)   // 392
#define PK_TOTAL (PK_WHH + PK_FUSE + PK_DEG + 1)

__global__ __launch_bounds__(256) void pack_all_kernel(
    const float* __restrict__ W, const float* __restrict__ W_ih,
    const float* __restrict__ W_hh,
    unsigned short* __restrict__ Whh_p, unsigned short* __restrict__ Wfuse_p,
    int* __restrict__ deg, float* __restrict__ out)
{
  const int b = blockIdx.x;
  const int tid = threadIdx.x;
  if (b < PK_WHH) {
    int t = b * 256 + tid;
    int i = t & 7, l = (t >> 3) & 63, q = t >> 9;      // q in [0,96)
    int ks = q & 7, cb = q >> 3;
    int k = ks * 16 + 8 * (l >> 5) + i;
    int o = cb * 32 + (l & 31);
    Whh_p[t] = f2bf(W_hh[(size_t)o * CC + k]);
  } else if (b < PK_WHH + PK_FUSE) {
    int idx = b - PK_WHH;
    int layer = idx / 192;
    int t = (idx % 192) * 256 + tid;
    int i = t & 7, l = (t >> 3) & 63, q = t >> 9;
    int ks = q & 7, cb = q >> 3;
    int k = ks * 16 + 8 * (l >> 5) + i;
    int o = cb * 32 + (l & 31);
    const float* wl = W + (size_t)layer * CC * CC + (size_t)k * CC;
    const float* wi = W_ih + (size_t)o * CC;
    float acc = 0.f;
    #pragma unroll 8
    for (int j = 0; j < CC; ++j) acc = fmaf(wl[j], wi[j], acc);
    Wfuse_p[(size_t)layer * 49152 + t] = f2bf(acc);
  } else if (b < PK_WHH + PK_FUSE + PK_DEG) {
    int i = (b - PK_WHH - PK_FUSE) * 256 + tid;
    if (i < NN + 256) deg[i] = 0;
  } else {
    #pragma unroll
    for (int i = 0; i < 4; ++i) out[i * 256 + tid] = 0.0f;
  }
}

// ---------------- CSR build (once per call) ----------------

__global__ __launch_bounds__(256) void hist_kernel(const int* __restrict__ eidx,
                                                   int* __restrict__ deg)
{
  int e = blockIdx.x * blockDim.x + threadIdx.x;
  if (e < EE) atomicAdd(&deg[eidx[EE + e]], 1);
}

__global__ __launch_bounds__(256) void scan1_kernel(const int* __restrict__ deg,
                                                    int* __restrict__ bsum)
{
  __shared__ int red[4];
  int base = blockIdx.x * 1024 + threadIdx.x * 4;
  int s = 0;
  #pragma unroll
  for (int i = 0; i < 4; ++i) { int idx = base + i; if (idx < NN) s += deg[idx]; }
  #pragma unroll
  for (int off = 32; off; off >>= 1) s += __shfl_down(s, off, 64);
  if ((threadIdx.x & 63) == 0) red[threadIdx.x >> 6] = s;
  __syncthreads();
  if (threadIdx.x == 0) bsum[blockIdx.x] = red[0] + red[1] + red[2] + red[3];
}

// wave-parallel exclusive scan of the 98-entry block-sum array
__global__ __launch_bounds__(64) void scan2_kernel(int* __restrict__ bsum, int nb)
{
  const int lane = threadIdx.x;
  int carry = 0;
  for (int base = 0; base < nb; base += 64) {
    int i = base + lane;
    int v = (i < nb) ? bsum[i] : 0;
    const int orig = v;
    #pragma unroll
    for (int off = 1; off < 64; off <<= 1) {
      int u = __shfl_up(v, off, 64);
      if (lane >= off) v += u;
    }
    if (i < nb) bsum[i] = v - orig + carry;
    carry += __shfl(v, 63, 64);
  }
}

__global__ __launch_bounds__(256) void scan3_kernel(const int* __restrict__ deg,
                                                    const int* __restrict__ bsum,
                                                    int* __restrict__ row_ptr,
                                                    int* __restrict__ cursor)
{
  __shared__ int ts[256];
  const int tid = threadIdx.x;
  const int base = blockIdx.x * 1024 + tid * 4;
  int v[4]; int s = 0;
  #pragma unroll
  for (int i = 0; i < 4; ++i) { int idx = base + i; v[i] = (idx < NN) ? deg[idx] : 0; s += v[i]; }
  ts[tid] = s; __syncthreads();
  for (int off = 1; off < 256; off <<= 1) {
    int t = (tid >= off) ? ts[tid - off] : 0;
    __syncthreads();
    ts[tid] += t;
    __syncthreads();
  }
  int excl = bsum[blockIdx.x] + ts[tid] - s;
  #pragma unroll
  for (int i = 0; i < 4; ++i) {
    int idx = base + i;
    if (idx < NN) { row_ptr[idx] = excl; cursor[idx] = excl; excl += v[i]; }
  }
  if (blockIdx.x == 0 && tid == 0) row_ptr[NN] = EE;
}

// direct single-phase fill: 100K cursors -> negligible contention; write amp accepted
__global__ __launch_bounds__(256) void fill_kernel(const int* __restrict__ eidx,
                                                   const float* __restrict__ ew,
                                                   int* __restrict__ cursor,
                                                   int2* __restrict__ csr_sw)
{
  int e = blockIdx.x * blockDim.x + threadIdx.x;
  if (e < EE) {
    int d = eidx[EE + e];
    int p = atomicAdd(&cursor[d], 1);
    csr_sw[p] = make_int2(eidx[e], __float_as_int(ew[e]));
  }
}

// ---------------- main pipeline ----------------

// h0 = x @ W_emb + b_emb; bf16 state
__global__ __launch_bounds__(128) void embed_kernel(
    const float* __restrict__ x, const float* __restrict__ W_emb,
    const float* __restrict__ b_emb, unsigned short* __restrict__ h_bf)
{
  const int node = blockIdx.x;
  const int c = threadIdx.x;
  float acc = b_emb[c];
  #pragma unroll
  for (int k = 0; k < 32; ++k)
    acc = fmaf(x[node * 32 + k], W_emb[k * CC + c], acc);
  h_bf[(size_t)node * CC + c] = f2bf(acc);
}

// CSR gather: one node per wave, 32 edges in flight (deg<=31 -> single iteration).
__global__ __launch_bounds__(256) void aggregate_kernel(
    const unsigned short* __restrict__ h_bf, const int* __restrict__ row_ptr,
    const int2* __restrict__ csr_sw, unsigned short* __restrict__ agg_bf)
{
  const int lane = threadIdx.x & 63;
  const int node = (blockIdx.x * blockDim.x + threadIdx.x) >> 6;
  if (node >= NN) return;
  const int q = lane >> 4;
  const int t = lane & 15;
  const int beg = row_ptr[node], end = row_ptr[node + 1];

  float acc[8] = {0.f, 0.f, 0.f, 0.f, 0.f, 0.f, 0.f, 0.f};
  const int last = end - 1;

  for (int j = beg; j < end; j += 32) {
    const int e0 = j + q,      e1 = j + 4 + q,  e2 = j + 8 + q,  e3 = j + 12 + q;
    const int e4 = j + 16 + q, e5 = j + 20 + q, e6 = j + 24 + q, e7 = j + 28 + q;
    const int2 r0 = csr_sw[min(e0, last)], r1 = csr_sw[min(e1, last)];
    const int2 r2 = csr_sw[min(e2, last)], r3 = csr_sw[min(e3, last)];
    const int2 r4 = csr_sw[min(e4, last)], r5 = csr_sw[min(e5, last)];
    const int2 r6 = csr_sw[min(e6, last)], r7 = csr_sw[min(e7, last)];
    const uint4 u0 = *(const uint4*)(h_bf + (size_t)r0.x * CC + t * 8);
    const uint4 u1 = *(const uint4*)(h_bf + (size_t)r1.x * CC + t * 8);
    const uint4 u2 = *(const uint4*)(h_bf + (size_t)r2.x * CC + t * 8);
    const uint4 u3 = *(const uint4*)(h_bf + (size_t)r3.x * CC + t * 8);
    const uint4 u4 = *(const uint4*)(h_bf + (size_t)r4.x * CC + t * 8);
    const uint4 u5 = *(const uint4*)(h_bf + (size_t)r5.x * CC + t * 8);
    const uint4 u6 = *(const uint4*)(h_bf + (size_t)r6.x * CC + t * 8);
    const uint4 u7 = *(const uint4*)(h_bf + (size_t)r7.x * CC + t * 8);
    const float w0 = (e0 < end) ? __int_as_float(r0.y) : 0.0f;
    const float w1 = (e1 < end) ? __int_as_float(r1.y) : 0.0f;
    const float w2 = (e2 < end) ? __int_as_float(r2.y) : 0.0f;
    const float w3 = (e3 < end) ? __int_as_float(r3.y) : 0.0f;
    const float w4 = (e4 < end) ? __int_as_float(r4.y) : 0.0f;
    const float w5 = (e5 < end) ? __int_as_float(r5.y) : 0.0f;
    const float w6 = (e6 < end) ? __int_as_float(r6.y) : 0.0f;
    const float w7 = (e7 < end) ? __int_as_float(r7.y) : 0.0f;

    acc[0] = fmaf(bflo(u0.x), w0, acc[0]); acc[1] = fmaf(bfhi(u0.x), w0, acc[1]);
    acc[2] = fmaf(bflo(u0.y), w0, acc[2]); acc[3] = fmaf(bfhi(u0.y), w0, acc[3]);
    acc[4] = fmaf(bflo(u0.z), w0, acc[4]); acc[5] = fmaf(bfhi(u0.z), w0, acc[5]);
    acc[6] = fmaf(bflo(u0.w), w0, acc[6]); acc[7] = fmaf(bfhi(u0.w), w0, acc[7]);
    acc[0] = fmaf(bflo(u1.x), w1, acc[0]); acc[1] = fmaf(bfhi(u1.x), w1, acc[1]);
    acc[2] = fmaf(bflo(u1.y), w1, acc[2]); acc[3] = fmaf(bfhi(u1.y), w1, acc[3]);
    acc[4] = fmaf(bflo(u1.z), w1, acc[4]); acc[5] = fmaf(bfhi(u1.z), w1, acc[5]);
    acc[6] = fmaf(bflo(u1.w), w1, acc[6]); acc[7] = fmaf(bfhi(u1.w), w1, acc[7]);
    acc[0] = fmaf(bflo(u2.x), w2, acc[0]); acc[1] = fmaf(bfhi(u2.x), w2, acc[1]);
    acc[2] = fmaf(bflo(u2.y), w2, acc[2]); acc[3] = fmaf(bfhi(u2.y), w2, acc[3]);
    acc[4] = fmaf(bflo(u2.z), w2, acc[4]); acc[5] = fmaf(bfhi(u2.z), w2, acc[5]);
    acc[6] = fmaf(bflo(u2.w), w2, acc[6]); acc[7] = fmaf(bfhi(u2.w), w2, acc[7]);
    acc[0] = fmaf(bflo(u3.x), w3, acc[0]); acc[1] = fmaf(bfhi(u3.x), w3, acc[1]);
    acc[2] = fmaf(bflo(u3.y), w3, acc[2]); acc[3] = fmaf(bfhi(u3.y), w3, acc[3]);
    acc[4] = fmaf(bflo(u3.z), w3, acc[4]); acc[5] = fmaf(bfhi(u3.z), w3, acc[5]);
    acc[6] = fmaf(bflo(u3.w), w3, acc[6]); acc[7] = fmaf(bfhi(u3.w), w3, acc[7]);
    acc[0] = fmaf(bflo(u4.x), w4, acc[0]); acc[1] = fmaf(bfhi(u4.x), w4, acc[1]);
    acc[2] = fmaf(bflo(u4.y), w4, acc[2]); acc[3] = fmaf(bfhi(u4.y), w4, acc[3]);
    acc[4] = fmaf(bflo(u4.z), w4, acc[4]); acc[5] = fmaf(bfhi(u4.z), w4, acc[5]);
    acc[6] = fmaf(bflo(u4.w), w4, acc[6]); acc[7] = fmaf(bfhi(u4.w), w4, acc[7]);
    acc[0] = fmaf(bflo(u5.x), w5, acc[0]); acc[1] = fmaf(bfhi(u5.x), w5, acc[1]);
    acc[2] = fmaf(bflo(u5.y), w5, acc[2]); acc[3] = fmaf(bfhi(u5.y), w5, acc[3]);
    acc[4] = fmaf(bflo(u5.z), w5, acc[4]); acc[5] = fmaf(bfhi(u5.z), w5, acc[5]);
    acc[6] = fmaf(bflo(u5.w), w5, acc[6]); acc[7] = fmaf(bfhi(u5.w), w5, acc[7]);
    acc[0] = fmaf(bflo(u6.x), w6, acc[0]); acc[1] = fmaf(bfhi(u6.x), w6, acc[1]);
    acc[2] = fmaf(bflo(u6.y), w6, acc[2]); acc[3] = fmaf(bfhi(u6.y), w6, acc[3]);
    acc[4] = fmaf(bflo(u6.z), w6, acc[4]); acc[5] = fmaf(bfhi(u6.z), w6, acc[5]);
    acc[6] = fmaf(bflo(u6.w), w6, acc[6]); acc[7] = fmaf(bfhi(u6.w), w6, acc[7]);
    acc[0] = fmaf(bflo(u7.x), w7, acc[0]); acc[1] = fmaf(bfhi(u7.x), w7, acc[1]);
    acc[2] = fmaf(bflo(u7.y), w7, acc[2]); acc[3] = fmaf(bfhi(u7.y), w7, acc[3]);
    acc[4] = fmaf(bflo(u7.z), w7, acc[4]); acc[5] = fmaf(bfhi(u7.z), w7, acc[5]);
    acc[6] = fmaf(bflo(u7.w), w7, acc[6]); acc[7] = fmaf(bfhi(u7.w), w7, acc[7]);
  }

  #pragma unroll
  for (int i = 0; i < 8; ++i) {
    acc[i] += __shfl_xor(acc[i], 16, 64);
    acc[i] += __shfl_xor(acc[i], 32, 64);
  }

  if (q == 0) {
    uint4 o;
    o.x = (unsigned)f2bf(acc[0]) | ((unsigned)f2bf(acc[1]) << 16);
    o.y = (unsigned)f2bf(acc[2]) | ((unsigned)f2bf(acc[3]) << 16);
    o.z = (unsigned)f2bf(acc[4]) | ((unsigned)f2bf(acc[5]) << 16);
    o.w = (unsigned)f2bf(acc[6]) | ((unsigned)f2bf(acc[7]) << 16);
    *(uint4*)(agg_bf + (size_t)node * CC + t * 8) = o;
  }
}

// GRU via 32x32x16 MFMA (halved B-traffic/FLOP vs 16x16x32). 32 nodes/wave.
// C/D map (HW-verified): col = lane&31, row = (reg&3) + 8*(reg>>2) + 4*(lane>>5).
// h snapshot in LDS for aH fragments + blend ho reads.
__global__ __launch_bounds__(256) void gru_kernel(
    const unsigned short* __restrict__ agg_bf, unsigned short* __restrict__ h_bf,
    const unsigned short* __restrict__ Wfuse_p, const unsigned short* __restrict__ Whh_p,
    const float* __restrict__ b_ih, const float* __restrict__ b_hh)
{
  __shared__ unsigned short hbuf[4][32][136];   // 128 + 8 pad
  const int lane = threadIdx.x & 63;
  const int wave = threadIdx.x >> 6;
  const int node0 = blockIdx.x * 128 + wave * 32;
  if (node0 >= NN) return;
  const int l31 = lane & 31;    // A: node row; B/C: output column
  const int kg = lane >> 5;     // k-group

  // snapshot 32 h rows (8KB) into LDS, vectorized + coalesced
  #pragma unroll
  for (int i = 0; i < 8; ++i) {
    const int chunk = lane + 64 * i;          // 0..511
    const int row = chunk >> 4, c16 = chunk & 15;
    uint4 v = *(const uint4*)(h_bf + (size_t)(node0 + row) * CC + c16 * 8);
    *(uint4*)&hbuf[wave][row][c16 * 8] = v;
  }

  // A fragments: k = ks*16 + kg*8 + i
  bf16x8 aA[8], aH[8];
  {
    const unsigned short* arow = agg_bf + (size_t)(node0 + l31) * CC + kg * 8;
    #pragma unroll
    for (int ks = 0; ks < 8; ++ks) {
      aA[ks] = *(const bf16x8*)(arow + ks * 16);
      aH[ks] = *(const bf16x8*)&hbuf[wave][l31][ks * 16 + kg * 8];
    }
  }

  const f32x16 z16 = {0.f};

  for (int cc = 0; cc < 4; ++cc) {
    f32x16 air = z16, ahr = z16, aiz = z16, ahz = z16, ain = z16, ahn = z16;
    #pragma unroll
    for (int ks = 0; ks < 8; ++ks) {
      const size_t fr = (size_t)(((cc     ) * 8 + ks) * 64 + lane) * 8;
      const size_t fz = (size_t)(((4 + cc) * 8 + ks) * 64 + lane) * 8;
      const size_t fn = (size_t)(((8 + cc) * 8 + ks) * 64 + lane) * 8;
      bf16x8 bir = *(const bf16x8*)(Wfuse_p + fr);
      bf16x8 bhr = *(const bf16x8*)(Whh_p + fr);
      bf16x8 biz = *(const bf16x8*)(Wfuse_p + fz);
      bf16x8 bhz = *(const bf16x8*)(Whh_p + fz);
      bf16x8 bin = *(const bf16x8*)(Wfuse_p + fn);
      bf16x8 bhn = *(const bf16x8*)(Whh_p + fn);
      air = __builtin_amdgcn_mfma_f32_32x32x16_bf16(aA[ks], bir, air, 0, 0, 0);
      ahr = __builtin_amdgcn_mfma_f32_32x32x16_bf16(aH[ks], bhr, ahr, 0, 0, 0);
      aiz = __builtin_amdgcn_mfma_f32_32x32x16_bf16(aA[ks], biz, aiz, 0, 0, 0);
      ahz = __builtin_amdgcn_mfma_f32_32x32x16_bf16(aH[ks], bhz, ahz, 0, 0, 0);
      ain = __builtin_amdgcn_mfma_f32_32x32x16_bf16(aA[ks], bin, ain, 0, 0, 0);
      ahn = __builtin_amdgcn_mfma_f32_32x32x16_bf16(aH[ks], bhn, ahn, 0, 0, 0);
    }
    const int o = cc * 32 + l31;              // hidden-unit column in [0,128)
    const float bir_ = b_ih[o],       bhr_ = b_hh[o];
    const float biz_ = b_ih[128 + o], bhz_ = b_hh[128 + o];
    const float bin_ = b_ih[256 + o], bhn_ = b_hh[256 + o];
    #pragma unroll
    for (int r = 0; r < 16; ++r) {
      const int row = (r & 3) + 8 * (r >> 2) + 4 * kg;
      float rr = sigmoidf_(air[r] + ahr[r] + bir_ + bhr_);
      float zz = sigmoidf_(aiz[r] + ahz[r] + biz_ + bhz_);
      float nn = tanhf_(ain[r] + bin_ + rr * (ahn[r] + bhn_));
      float ho = bf2f(hbuf[wave][row][o]);
      h_bf[(size_t)(node0 + row) * CC + o] = f2bf((1.0f - zz) * nn + zz * ho);
    }
  }
}

// out[batch[n]] += h[n] . W_prop + b_prop   (wave per node; bf16 h)
__global__ __launch_bounds__(256) void prop_kernel(
    const unsigned short* __restrict__ h_bf, const int* __restrict__ batch,
    const float* __restrict__ Wp, const float* __restrict__ bp,
    float* __restrict__ out)
{
  const int lane = threadIdx.x & 63;
  const int wid = (blockIdx.x * blockDim.x + threadIdx.x) >> 6;
  const int nw = (gridDim.x * blockDim.x) >> 6;
  for (int node = wid; node < NN; node += nw) {
    unsigned int u = *(const unsigned int*)(h_bf + (size_t)node * CC + 2 * lane);
    float v = bflo(u) * Wp[2 * lane] + bfhi(u) * Wp[2 * lane + 1];
    #pragma unroll
    for (int off = 32; off > 0; off >>= 1) v += __shfl_down(v, off, 64);
    if (lane == 0) atomicAdd(&out[batch[node]], v + bp[0]);
  }
}

extern "C" void kernel_launch(void* const* d_in, const int* in_sizes, int n_in,
                              void* d_out, int out_size, void* d_ws, size_t ws_size,
                              hipStream_t stream)
{
  const float* x      = (const float*)d_in[0];
  const int*   eidx   = (const int*)d_in[1];
  const float* ew     = (const float*)d_in[2];
  const int*   batch  = (const int*)d_in[3];
  const float* W_emb  = (const float*)d_in[4];
  const float* b_emb  = (const float*)d_in[5];
  const float* W      = (const float*)d_in[6];
  const float* W_ih   = (const float*)d_in[7];
  const float* W_hh   = (const float*)d_in[8];
  const float* b_ih   = (const float*)d_in[9];
  const float* b_hh   = (const float*)d_in[10];
  const float* W_prop = (const float*)d_in[11];
  const float* b_prop = (const float*)d_in[12];
  float* out = (float*)d_out;

  // workspace layout (~66 MB)
  char* p = (char*)d_ws;
  unsigned short* h_bf  = (unsigned short*)p; p += (size_t)NN * CC * sizeof(short);  // 25.6 MB
  unsigned short* agg   = (unsigned short*)p; p += (size_t)NN * CC * sizeof(short);  // 25.6 MB
  int2* csr_sw          = (int2*)p;           p += (size_t)EE * sizeof(int2);        // 12.8 MB
  unsigned short* Wfuse_p = (unsigned short*)p; p += (size_t)LL * 49152 * sizeof(short);
  unsigned short* Whh_p = (unsigned short*)p; p += (size_t)49152 * sizeof(short);
  int* deg     = (int*)p;                     p += (size_t)(NN + 256) * sizeof(int);
  int* row_ptr = (int*)p;                     p += (size_t)(NN + 256) * sizeof(int);
  int* cursor  = (int*)p;                     p += (size_t)(NN + 256) * sizeof(int);
  int* bsum    = (int*)p;                     p += 1024 * sizeof(int);

  const int NB_SCAN = (NN + 1023) / 1024;   // 98
  const int EB = (EE + 255) / 256;          // 6250
  const int MB2 = (NN + 127) / 128;         // 782

  // ---- fused prepack + zero-init (deg, out) ----
  pack_all_kernel<<<PK_TOTAL, 256, 0, stream>>>(W, W_ih, W_hh, Whh_p, Wfuse_p, deg, out);

  // ---- CSR build (direct scatter fill) ----
  hist_kernel<<<EB, 256, 0, stream>>>(eidx, deg);
  scan1_kernel<<<NB_SCAN, 256, 0, stream>>>(deg, bsum);
  scan2_kernel<<<1, 64, 0, stream>>>(bsum, NB_SCAN);
  scan3_kernel<<<NB_SCAN, 256, 0, stream>>>(deg, bsum, row_ptr, cursor);
  fill_kernel<<<EB, 256, 0, stream>>>(eidx, ew, cursor, csr_sw);

  // ---- main pipeline (in-place h) ----
  embed_kernel<<<NN, 128, 0, stream>>>(x, W_emb, b_emb, h_bf);

  for (int l = 0; l < LL; ++l) {
    aggregate_kernel<<<(NN + 3) / 4, 256, 0, stream>>>(h_bf, row_ptr, csr_sw, agg);
    gru_kernel<<<MB2, 256, 0, stream>>>(agg, h_bf,
                                        Wfuse_p + (size_t)l * 49152, Whh_p, b_ih, b_hh);
  }

  prop_kernel<<<2048, 256, 0, stream>>>(h_bf, batch, W_prop, b_prop, out);
}

// Round 13
// 876.180 us; speedup vs baseline: 1.5263x; 1.5263x over previous
//
#include <hip/hip_runtime.h>

#define NN 100000
#define CC 128
#define EE 1600000
#define GG 1024
#define LL 5

typedef __attribute__((ext_vector_type(8))) short bf16x8;
typedef __attribute__((ext_vector_type(4))) float f32x4;

__device__ __forceinline__ float sigmoidf_(float x) { return 1.0f / (1.0f + __expf(-x)); }
__device__ __forceinline__ float tanhf_(float x) {
  float xx = fminf(15.0f, fmaxf(-15.0f, x));
  float t = __expf(-2.0f * xx);
  return (1.0f - t) / (1.0f + t);
}
__device__ __forceinline__ unsigned short f2bf(float x) {
  unsigned int u = __float_as_uint(x);
  return (unsigned short)((u + 0x7fffu + ((u >> 16) & 1u)) >> 16);
}
__device__ __forceinline__ float bflo(unsigned int u) { return __uint_as_float(u << 16); }
__device__ __forceinline__ float bfhi(unsigned int u) { return __uint_as_float(u & 0xffff0000u); }
__device__ __forceinline__ float bf2f(unsigned short v) { return __uint_as_float((unsigned)v << 16); }

// ---------------- fused prepack + zero-init kernel (one launch) ----------------
// Packed B-fragment layout: element (k, c) at t = ((cb*4+ks)*64 + l)*8 + i
// with k = ks*32 + 8*(l>>4) + i, c = cb*16 + (l&15).
#define PK_WHH 192
#define PK_FUSE (192 * LL)
#define PK_DEG ((NN + 256 + 255) / 256)   // 392
#define PK_TOTAL (PK_WHH + PK_FUSE + PK_DEG + 1)

__global__ __launch_bounds__(256) void pack_all_kernel(
    const float* __restrict__ W, const float* __restrict__ W_ih,
    const float* __restrict__ W_hh,
    unsigned short* __restrict__ Whh_p, unsigned short* __restrict__ Wfuse_p,
    int* __restrict__ deg, float* __restrict__ out)
{
  const int b = blockIdx.x;
  const int tid = threadIdx.x;
  if (b < PK_WHH) {
    int t = b * 256 + tid;
    int i = t & 7, l = (t >> 3) & 63, q = t >> 9;
    int ks = q & 3, cb = q >> 2;
    int k = ks * 32 + 8 * (l >> 4) + i;
    int c = cb * 16 + (l & 15);
    Whh_p[t] = f2bf(W_hh[(size_t)c * CC + k]);
  } else if (b < PK_WHH + PK_FUSE) {
    int idx = b - PK_WHH;
    int layer = idx / 192;
    int t = (idx % 192) * 256 + tid;
    int i = t & 7, l = (t >> 3) & 63, q = t >> 9;
    int ks = q & 3, cb = q >> 2;
    int k = ks * 32 + 8 * (l >> 4) + i;
    int c = cb * 16 + (l & 15);
    const float* wl = W + (size_t)layer * CC * CC + (size_t)k * CC;
    const float* wi = W_ih + (size_t)c * CC;
    float acc = 0.f;
    #pragma unroll 8
    for (int j = 0; j < CC; ++j) acc = fmaf(wl[j], wi[j], acc);
    Wfuse_p[(size_t)layer * 49152 + t] = f2bf(acc);
  } else if (b < PK_WHH + PK_FUSE + PK_DEG) {
    int i = (b - PK_WHH - PK_FUSE) * 256 + tid;
    if (i < NN + 256) deg[i] = 0;
  } else {
    #pragma unroll
    for (int i = 0; i < 4; ++i) out[i * 256 + tid] = 0.0f;
  }
}

// ---------------- CSR build (once per call) ----------------

__global__ __launch_bounds__(256) void hist_kernel(const int* __restrict__ eidx,
                                                   int* __restrict__ deg)
{
  int e = blockIdx.x * blockDim.x + threadIdx.x;
  if (e < EE) atomicAdd(&deg[eidx[EE + e]], 1);
}

__global__ __launch_bounds__(256) void scan1_kernel(const int* __restrict__ deg,
                                                    int* __restrict__ bsum)
{
  __shared__ int red[4];
  int base = blockIdx.x * 1024 + threadIdx.x * 4;
  int s = 0;
  #pragma unroll
  for (int i = 0; i < 4; ++i) { int idx = base + i; if (idx < NN) s += deg[idx]; }
  #pragma unroll
  for (int off = 32; off; off >>= 1) s += __shfl_down(s, off, 64);
  if ((threadIdx.x & 63) == 0) red[threadIdx.x >> 6] = s;
  __syncthreads();
  if (threadIdx.x == 0) bsum[blockIdx.x] = red[0] + red[1] + red[2] + red[3];
}

// wave-parallel exclusive scan of the 98-entry block-sum array
__global__ __launch_bounds__(64) void scan2_kernel(int* __restrict__ bsum, int nb)
{
  const int lane = threadIdx.x;
  int carry = 0;
  for (int base = 0; base < nb; base += 64) {
    int i = base + lane;
    int v = (i < nb) ? bsum[i] : 0;
    const int orig = v;
    #pragma unroll
    for (int off = 1; off < 64; off <<= 1) {
      int u = __shfl_up(v, off, 64);
      if (lane >= off) v += u;
    }
    if (i < nb) bsum[i] = v - orig + carry;
    carry += __shfl(v, 63, 64);
  }
}

__global__ __launch_bounds__(256) void scan3_kernel(const int* __restrict__ deg,
                                                    const int* __restrict__ bsum,
                                                    int* __restrict__ row_ptr,
                                                    int* __restrict__ cursor)
{
  __shared__ int ts[256];
  const int tid = threadIdx.x;
  const int base = blockIdx.x * 1024 + tid * 4;
  int v[4]; int s = 0;
  #pragma unroll
  for (int i = 0; i < 4; ++i) { int idx = base + i; v[i] = (idx < NN) ? deg[idx] : 0; s += v[i]; }
  ts[tid] = s; __syncthreads();
  for (int off = 1; off < 256; off <<= 1) {
    int t = (tid >= off) ? ts[tid - off] : 0;
    __syncthreads();
    ts[tid] += t;
    __syncthreads();
  }
  int excl = bsum[blockIdx.x] + ts[tid] - s;
  #pragma unroll
  for (int i = 0; i < 4; ++i) {
    int idx = base + i;
    if (idx < NN) { row_ptr[idx] = excl; cursor[idx] = excl; excl += v[i]; }
  }
  if (blockIdx.x == 0 && tid == 0) row_ptr[NN] = EE;
}

// direct single-phase fill: 100K cursors -> negligible contention; write amp accepted
__global__ __launch_bounds__(256) void fill_kernel(const int* __restrict__ eidx,
                                                   const float* __restrict__ ew,
                                                   int* __restrict__ cursor,
                                                   int2* __restrict__ csr_sw)
{
  int e = blockIdx.x * blockDim.x + threadIdx.x;
  if (e < EE) {
    int d = eidx[EE + e];
    int p = atomicAdd(&cursor[d], 1);
    csr_sw[p] = make_int2(eidx[e], __float_as_int(ew[e]));
  }
}

// ---------------- main pipeline ----------------

// h0 = x @ W_emb + b_emb; bf16 state
__global__ __launch_bounds__(128) void embed_kernel(
    const float* __restrict__ x, const float* __restrict__ W_emb,
    const float* __restrict__ b_emb, unsigned short* __restrict__ h_bf)
{
  const int node = blockIdx.x;
  const int c = threadIdx.x;
  float acc = b_emb[c];
  #pragma unroll
  for (int k = 0; k < 32; ++k)
    acc = fmaf(x[node * 32 + k], W_emb[k * CC + c], acc);
  h_bf[(size_t)node * CC + c] = f2bf(acc);
}

// CSR gather: one node per wave, 16 edges in flight.
__global__ __launch_bounds__(256) void aggregate_kernel(
    const unsigned short* __restrict__ h_bf, const int* __restrict__ row_ptr,
    const int2* __restrict__ csr_sw, unsigned short* __restrict__ agg_bf)
{
  const int lane = threadIdx.x & 63;
  const int node = (blockIdx.x * blockDim.x + threadIdx.x) >> 6;
  if (node >= NN) return;
  const int q = lane >> 4;
  const int t = lane & 15;
  const int beg = row_ptr[node], end = row_ptr[node + 1];

  float acc[8] = {0.f, 0.f, 0.f, 0.f, 0.f, 0.f, 0.f, 0.f};
  const int last = end - 1;

  for (int j = beg; j < end; j += 16) {
    const int e0 = j + q, e1 = j + 4 + q, e2 = j + 8 + q, e3 = j + 12 + q;
    const int i0 = min(e0, last), i1 = min(e1, last);
    const int i2 = min(e2, last), i3 = min(e3, last);
    const int2 r0 = csr_sw[i0], r1 = csr_sw[i1], r2 = csr_sw[i2], r3 = csr_sw[i3];
    const float w0 = (e0 < end) ? __int_as_float(r0.y) : 0.0f;
    const float w1 = (e1 < end) ? __int_as_float(r1.y) : 0.0f;
    const float w2 = (e2 < end) ? __int_as_float(r2.y) : 0.0f;
    const float w3 = (e3 < end) ? __int_as_float(r3.y) : 0.0f;
    const uint4 u0 = *(const uint4*)(h_bf + (size_t)r0.x * CC + t * 8);
    const uint4 u1 = *(const uint4*)(h_bf + (size_t)r1.x * CC + t * 8);
    const uint4 u2 = *(const uint4*)(h_bf + (size_t)r2.x * CC + t * 8);
    const uint4 u3 = *(const uint4*)(h_bf + (size_t)r3.x * CC + t * 8);
    acc[0] = fmaf(bflo(u0.x), w0, acc[0]); acc[1] = fmaf(bfhi(u0.x), w0, acc[1]);
    acc[2] = fmaf(bflo(u0.y), w0, acc[2]); acc[3] = fmaf(bfhi(u0.y), w0, acc[3]);
    acc[4] = fmaf(bflo(u0.z), w0, acc[4]); acc[5] = fmaf(bfhi(u0.z), w0, acc[5]);
    acc[6] = fmaf(bflo(u0.w), w0, acc[6]); acc[7] = fmaf(bfhi(u0.w), w0, acc[7]);
    acc[0] = fmaf(bflo(u1.x), w1, acc[0]); acc[1] = fmaf(bfhi(u1.x), w1, acc[1]);
    acc[2] = fmaf(bflo(u1.y), w1, acc[2]); acc[3] = fmaf(bfhi(u1.y), w1, acc[3]);
    acc[4] = fmaf(bflo(u1.z), w1, acc[4]); acc[5] = fmaf(bfhi(u1.z), w1, acc[5]);
    acc[6] = fmaf(bflo(u1.w), w1, acc[6]); acc[7] = fmaf(bfhi(u1.w), w1, acc[7]);
    acc[0] = fmaf(bflo(u2.x), w2, acc[0]); acc[1] = fmaf(bfhi(u2.x), w2, acc[1]);
    acc[2] = fmaf(bflo(u2.y), w2, acc[2]); acc[3] = fmaf(bfhi(u2.y), w2, acc[3]);
    acc[4] = fmaf(bflo(u2.z), w2, acc[4]); acc[5] = fmaf(bfhi(u2.z), w2, acc[5]);
    acc[6] = fmaf(bflo(u2.w), w2, acc[6]); acc[7] = fmaf(bfhi(u2.w), w2, acc[7]);
    acc[0] = fmaf(bflo(u3.x), w3, acc[0]); acc[1] = fmaf(bfhi(u3.x), w3, acc[1]);
    acc[2] = fmaf(bflo(u3.y), w3, acc[2]); acc[3] = fmaf(bfhi(u3.y), w3, acc[3]);
    acc[4] = fmaf(bflo(u3.z), w3, acc[4]); acc[5] = fmaf(bfhi(u3.z), w3, acc[5]);
    acc[6] = fmaf(bflo(u3.w), w3, acc[6]); acc[7] = fmaf(bfhi(u3.w), w3, acc[7]);
  }

  #pragma unroll
  for (int i = 0; i < 8; ++i) {
    acc[i] += __shfl_xor(acc[i], 16, 64);
    acc[i] += __shfl_xor(acc[i], 32, 64);
  }

  if (q == 0) {
    uint4 o;
    o.x = (unsigned)f2bf(acc[0]) | ((unsigned)f2bf(acc[1]) << 16);
    o.y = (unsigned)f2bf(acc[2]) | ((unsigned)f2bf(acc[3]) << 16);
    o.z = (unsigned)f2bf(acc[4]) | ((unsigned)f2bf(acc[5]) << 16);
    o.w = (unsigned)f2bf(acc[6]) | ((unsigned)f2bf(acc[7]) << 16);
    *(uint4*)(agg_bf + (size_t)node * CC + t * 8) = o;
  }
}

// GRU via 16x16x32 MFMA, in-place h. Wave snapshot of its 32 h-rows in LDS.
__global__ __launch_bounds__(256) void gru_kernel(
    const unsigned short* __restrict__ agg_bf, unsigned short* __restrict__ h_bf,
    const unsigned short* __restrict__ Wfuse_p, const unsigned short* __restrict__ Whh_p,
    const float* __restrict__ b_ih, const float* __restrict__ b_hh)
{
  __shared__ unsigned short hbuf[4][32][136];   // 136 = 128 + 8 pad
  const int lane = threadIdx.x & 63;
  const int wave = threadIdx.x >> 6;
  const int node0 = blockIdx.x * 128 + wave * 32;
  if (node0 >= NN) return;
  const int col16 = lane & 15, grp = lane >> 4;

  // snapshot 32 rows (8KB) into LDS, vectorized + coalesced
  #pragma unroll
  for (int i = 0; i < 8; ++i) {
    const int chunk = lane + 64 * i;          // 0..511
    const int row = chunk >> 4, c16 = chunk & 15;
    uint4 v = *(const uint4*)(h_bf + (size_t)(node0 + row) * CC + c16 * 8);
    *(uint4*)&hbuf[wave][row][c16 * 8] = v;
  }

  bf16x8 aA[2][4], aH[2][4];
  #pragma unroll
  for (int t = 0; t < 2; ++t) {
    const unsigned short* arow = agg_bf + (size_t)(node0 + t * 16 + col16) * CC + grp * 8;
    #pragma unroll
    for (int ks = 0; ks < 4; ++ks) {
      aA[t][ks] = *(const bf16x8*)(arow + ks * 32);
      aH[t][ks] = *(const bf16x8*)&hbuf[wave][t * 16 + col16][grp * 8 + ks * 32];
    }
  }

  const f32x4 z4 = {0.f, 0.f, 0.f, 0.f};

  #pragma unroll
  for (int cb = 0; cb < 8; ++cb) {
    f32x4 air[2] = {z4, z4}, ahr[2] = {z4, z4};
    f32x4 aiz[2] = {z4, z4}, ahz[2] = {z4, z4};
    f32x4 ain[2] = {z4, z4}, ahn[2] = {z4, z4};
    #pragma unroll
    for (int ks = 0; ks < 4; ++ks) {
      const size_t or_ = (size_t)((cb * 4 + ks) * 64 + lane) * 8;
      const size_t oz_ = (size_t)(((8 + cb) * 4 + ks) * 64 + lane) * 8;
      const size_t on_ = (size_t)(((16 + cb) * 4 + ks) * 64 + lane) * 8;
      bf16x8 bir = *(const bf16x8*)(Wfuse_p + or_);
      bf16x8 bhr = *(const bf16x8*)(Whh_p + or_);
      bf16x8 biz = *(const bf16x8*)(Wfuse_p + oz_);
      bf16x8 bhz = *(const bf16x8*)(Whh_p + oz_);
      bf16x8 bin = *(const bf16x8*)(Wfuse_p + on_);
      bf16x8 bhn = *(const bf16x8*)(Whh_p + on_);
      #pragma unroll
      for (int t = 0; t < 2; ++t) {
        air[t] = __builtin_amdgcn_mfma_f32_16x16x32_bf16(aA[t][ks], bir, air[t], 0, 0, 0);
        ahr[t] = __builtin_amdgcn_mfma_f32_16x16x32_bf16(aH[t][ks], bhr, ahr[t], 0, 0, 0);
        aiz[t] = __builtin_amdgcn_mfma_f32_16x16x32_bf16(aA[t][ks], biz, aiz[t], 0, 0, 0);
        ahz[t] = __builtin_amdgcn_mfma_f32_16x16x32_bf16(aH[t][ks], bhz, ahz[t], 0, 0, 0);
        ain[t] = __builtin_amdgcn_mfma_f32_16x16x32_bf16(aA[t][ks], bin, ain[t], 0, 0, 0);
        ahn[t] = __builtin_amdgcn_mfma_f32_16x16x32_bf16(aH[t][ks], bhn, ahn[t], 0, 0, 0);
      }
    }
    const int o = cb * 16 + col16;
    const float bir_ = b_ih[o],       bhr_ = b_hh[o];
    const float biz_ = b_ih[128 + o], bhz_ = b_hh[128 + o];
    const float bin_ = b_ih[256 + o], bhn_ = b_hh[256 + o];
    #pragma unroll
    for (int t = 0; t < 2; ++t) {
      #pragma unroll
      for (int r = 0; r < 4; ++r) {
        float rr = sigmoidf_(air[t][r] + ahr[t][r] + bir_ + bhr_);
        float zz = sigmoidf_(aiz[t][r] + ahz[t][r] + biz_ + bhz_);
        float nn = tanhf_(ain[t][r] + bin_ + rr * (ahn[t][r] + bhn_));
        const int row = t * 16 + grp * 4 + r;
        float ho = bf2f(hbuf[wave][row][o]);
        h_bf[(size_t)(node0 + row) * CC + o] = f2bf((1.0f - zz) * nn + zz * ho);
      }
    }
  }
}

// out[batch[n]] += h[n] . W_prop + b_prop   (wave per node; bf16 h)
__global__ __launch_bounds__(256) void prop_kernel(
    const unsigned short* __restrict__ h_bf, const int* __restrict__ batch,
    const float* __restrict__ Wp, const float* __restrict__ bp,
    float* __restrict__ out)
{
  const int lane = threadIdx.x & 63;
  const int wid = (blockIdx.x * blockDim.x + threadIdx.x) >> 6;
  const int nw = (gridDim.x * blockDim.x) >> 6;
  for (int node = wid; node < NN; node += nw) {
    unsigned int u = *(const unsigned int*)(h_bf + (size_t)node * CC + 2 * lane);
    float v = bflo(u) * Wp[2 * lane] + bfhi(u) * Wp[2 * lane + 1];
    #pragma unroll
    for (int off = 32; off > 0; off >>= 1) v += __shfl_down(v, off, 64);
    if (lane == 0) atomicAdd(&out[batch[node]], v + bp[0]);
  }
}

extern "C" void kernel_launch(void* const* d_in, const int* in_sizes, int n_in,
                              void* d_out, int out_size, void* d_ws, size_t ws_size,
                              hipStream_t stream)
{
  const float* x      = (const float*)d_in[0];
  const int*   eidx   = (const int*)d_in[1];
  const float* ew     = (const float*)d_in[2];
  const int*   batch  = (const int*)d_in[3];
  const float* W_emb  = (const float*)d_in[4];
  const float* b_emb  = (const float*)d_in[5];
  const float* W      = (const float*)d_in[6];
  const float* W_ih   = (const float*)d_in[7];
  const float* W_hh   = (const float*)d_in[8];
  const float* b_ih   = (const float*)d_in[9];
  const float* b_hh   = (const float*)d_in[10];
  const float* W_prop = (const float*)d_in[11];
  const float* b_prop = (const float*)d_in[12];
  float* out = (float*)d_out;

  // workspace layout (~66 MB)
  char* p = (char*)d_ws;
  unsigned short* h_bf  = (unsigned short*)p; p += (size_t)NN * CC * sizeof(short);  // 25.6 MB
  unsigned short* agg   = (unsigned short*)p; p += (size_t)NN * CC * sizeof(short);  // 25.6 MB
  int2* csr_sw          = (int2*)p;           p += (size_t)EE * sizeof(int2);        // 12.8 MB
  unsigned short* Wfuse_p = (unsigned short*)p; p += (size_t)LL * 49152 * sizeof(short);
  unsigned short* Whh_p = (unsigned short*)p; p += (size_t)49152 * sizeof(short);
  int* deg     = (int*)p;                     p += (size_t)(NN + 256) * sizeof(int);
  int* row_ptr = (int*)p;                     p += (size_t)(NN + 256) * sizeof(int);
  int* cursor  = (int*)p;                     p += (size_t)(NN + 256) * sizeof(int);
  int* bsum    = (int*)p;                     p += 1024 * sizeof(int);

  const int NB_SCAN = (NN + 1023) / 1024;   // 98
  const int EB = (EE + 255) / 256;          // 6250
  const int MB2 = (NN + 127) / 128;         // 782

  // ---- fused prepack + zero-init (deg, out) ----
  pack_all_kernel<<<PK_TOTAL, 256, 0, stream>>>(W, W_ih, W_hh, Whh_p, Wfuse_p, deg, out);

  // ---- CSR build (direct scatter fill) ----
  hist_kernel<<<EB, 256, 0, stream>>>(eidx, deg);
  scan1_kernel<<<NB_SCAN, 256, 0, stream>>>(deg, bsum);
  scan2_kernel<<<1, 64, 0, stream>>>(bsum, NB_SCAN);
  scan3_kernel<<<NB_SCAN, 256, 0, stream>>>(deg, bsum, row_ptr, cursor);
  fill_kernel<<<EB, 256, 0, stream>>>(eidx, ew, cursor, csr_sw);

  // ---- main pipeline (in-place h) ----
  embed_kernel<<<NN, 128, 0, stream>>>(x, W_emb, b_emb, h_bf);

  for (int l = 0; l < LL; ++l) {
    aggregate_kernel<<<(NN + 3) / 4, 256, 0, stream>>>(h_bf, row_ptr, csr_sw, agg);
    gru_kernel<<<MB2, 256, 0, stream>>>(agg, h_bf,
                                        Wfuse_p + (size_t)l * 49152, Whh_p, b_ih, b_hh);
  }

  prop_kernel<<<2048, 256, 0, stream>>>(h_bf, batch, W_prop, b_prop, out);
}